// Round 13
// baseline (299.527 us; speedup 1.0000x reference)
//
#include <hip/hip_runtime.h>
#include <hip/hip_bf16.h>
#include <math.h>

#define B_  2
#define L_  2048
#define D_  256
#define H_  8
#define HD_ 32
#define F_  1024
#define LY_ 4
#define M_  (B_*L_)

typedef __attribute__((ext_vector_type(8))) short bf16x8;   // 8 bf16 in 4 VGPRs
typedef __attribute__((ext_vector_type(4))) float f32x4;

static __device__ __forceinline__ short f2bf(float f) {
    return __builtin_bit_cast(short, __float2bfloat16(f));
}

static __device__ __forceinline__ void gload_lds16(const ushort* g, ushort* l) {
    __builtin_amdgcn_global_load_lds(
        (const __attribute__((address_space(1))) void*)g,
        (__attribute__((address_space(3))) void*)l, 16, 0, 0);
}

// ---------------------------------------------------------------------------
// Weight transpose + fp32->bf16:  W[K][N] -> Wt[N][K] bf16  (round-6 verified)
// ---------------------------------------------------------------------------
__global__ __launch_bounds__(256) void transpose_weights(
    const float* __restrict__ Win, const float* __restrict__ Wq,
    const float* __restrict__ Wk,  const float* __restrict__ Wv,
    const float* __restrict__ Wo,  const float* __restrict__ W1,
    const float* __restrict__ W2,  const float* __restrict__ Wout,
    ushort* __restrict__ T)
{
    const int bid = blockIdx.x;
    const float* src; ushort* dst; int K, N, tt;
    if (bid < 64)        { src = Win; dst = T; K = 256; N = 256; tt = bid; }
    else if (bid < 1088) {
        int i = bid - 64; int which = i >> 8; int l = (i >> 6) & 3; tt = i & 63;
        K = 256; N = 256;
        const float* s4[4] = {Wq, Wk, Wv, Wo};
        src = s4[which] + l * 65536;
        dst = T + 65536 * (1 + which * 4 + l);
    } else if (bid < 2112) {
        int i = bid - 1088; int l = i >> 8; tt = i & 255; K = 256; N = 1024;
        src = W1 + l * 262144; dst = T + 65536 * 17 + l * 262144;
    } else if (bid < 3136) {
        int i = bid - 2112; int l = i >> 8; tt = i & 255; K = 1024; N = 256;
        src = W2 + l * 262144; dst = T + 65536 * 17 + 1048576 + l * 262144;
    } else {
        src = Wout; dst = T + 65536 * 17 + 2097152; K = 256; N = 256; tt = bid - 3136;
    }
    const int ntn = N >> 5;
    const int tk = tt / ntn, tn = tt % ntn;
    __shared__ float ld[32][33];
    const int t = threadIdx.x;
    const int r = t >> 3, c4 = (t & 7) * 4;
    float4 v = *reinterpret_cast<const float4*>(&src[(size_t)(tk * 32 + r) * N + tn * 32 + c4]);
    ld[r][c4 + 0] = v.x; ld[r][c4 + 1] = v.y; ld[r][c4 + 2] = v.z; ld[r][c4 + 3] = v.w;
    __syncthreads();
    short4 o;
    o.x = f2bf(ld[c4 + 0][r]);
    o.y = f2bf(ld[c4 + 1][r]);
    o.z = f2bf(ld[c4 + 2][r]);
    o.w = f2bf(ld[c4 + 3][r]);
    *reinterpret_cast<short4*>(&dst[(size_t)(tn * 32 + r) * K + tk * 32 + c4]) = o;
}

// ---------------------------------------------------------------------------
__global__ __launch_bounds__(256) void f32_to_bf16(
    const float* __restrict__ in, ushort* __restrict__ out)
{
    const int i = (blockIdx.x * 256 + threadIdx.x) * 4;
    float4 v = *reinterpret_cast<const float4*>(&in[i]);
    short4 o = {f2bf(v.x), f2bf(v.y), f2bf(v.z), f2bf(v.w)};
    *reinterpret_cast<short4*>(&out[i]) = o;
}

// ---------------------------------------------------------------------------
// bf16 MFMA GEMM core v2 (round-6 verified, 64x64 tile): async staging,
// double-buffered, one barrier per BK=64, both-sides XOR swizzle.
// ---------------------------------------------------------------------------
__device__ __forceinline__ void gemm_core64(
    const ushort* __restrict__ A, const ushort* __restrict__ Wt, int K,
    int row0, int col0, ushort* sA, ushort* sW, f32x4 acc[2][2])
{
    const int tid  = threadIdx.x;
    const int lane = tid & 63;
    const int wid  = tid >> 6;
    const int wr = wid >> 1, wc = wid & 1;
    const int g = lane >> 4, nn = lane & 15;

    const int r0 = tid >> 3;
    const int sx = ((tid & 7) ^ (r0 & 7)) << 3;

    const ushort* Ap = &A[(size_t)(row0 + r0) * K + sx];
    const ushort* Wp = &Wt[(size_t)(col0 + r0) * K + sx];
    const size_t rstep = (size_t)32 * K;

    ushort* ldsA = sA + wid * 512;
    ushort* ldsW = sW + wid * 512;

    gload_lds16(Ap,         ldsA);
    gload_lds16(Ap + rstep, ldsA + 2048);
    gload_lds16(Wp,         ldsW);
    gload_lds16(Wp + rstep, ldsW + 2048);

    const int ra = (wr * 32 + nn) * 64, rb = ra + 16 * 64;
    const int rc = (wc * 32 + nn) * 64, rd = rc + 16 * 64;
    const int m7 = nn & 7;

    int cur = 0;
    __syncthreads();
    for (int k0 = 0; k0 < K; k0 += 64) {
        if (k0 + 64 < K) {
            ushort* lA = ldsA + (cur ^ 1) * 4096;
            ushort* lW = ldsW + (cur ^ 1) * 4096;
            gload_lds16(Ap + k0 + 64,         lA);
            gload_lds16(Ap + k0 + 64 + rstep, lA + 2048);
            gload_lds16(Wp + k0 + 64,         lW);
            gload_lds16(Wp + k0 + 64 + rstep, lW + 2048);
        }
        const ushort* a = sA + cur * 4096;
        const ushort* w = sW + cur * 4096;
#pragma unroll
        for (int sk = 0; sk < 2; ++sk) {
            const int sw = ((sk * 4 + g) ^ m7) << 3;
            bf16x8 a0 = *reinterpret_cast<const bf16x8*>(&a[ra + sw]);
            bf16x8 a1 = *reinterpret_cast<const bf16x8*>(&a[rb + sw]);
            bf16x8 w0 = *reinterpret_cast<const bf16x8*>(&w[rc + sw]);
            bf16x8 w1 = *reinterpret_cast<const bf16x8*>(&w[rd + sw]);
            acc[0][0] = __builtin_amdgcn_mfma_f32_16x16x32_bf16(a0, w0, acc[0][0], 0, 0, 0);
            acc[0][1] = __builtin_amdgcn_mfma_f32_16x16x32_bf16(a0, w1, acc[0][1], 0, 0, 0);
            acc[1][0] = __builtin_amdgcn_mfma_f32_16x16x32_bf16(a1, w0, acc[1][0], 0, 0, 0);
            acc[1][1] = __builtin_amdgcn_mfma_f32_16x16x32_bf16(a1, w1, acc[1][1], 0, 0, 0);
        }
        __syncthreads();
        cur ^= 1;
    }
}

// ---------------------------------------------------------------------------
// 32x64-tile core: same staging pattern / swizzle / fragment maps, A-tile
// halved to 32 rows -> grid doubles to 512 blocks = 2 blocks/CU, so one
// block's MFMA phase overlaps the other's barrier vmcnt-drain stall.
// Wave layout 2x2, sub-tile 16x32. A-swizzle key (row&7) == nn&7 preserved.
// ---------------------------------------------------------------------------
__device__ __forceinline__ void gemm_core32(
    const ushort* __restrict__ A, const ushort* __restrict__ Wt, int K,
    int row0, int col0, ushort* sA, ushort* sW, f32x4 acc[2])
{
    const int tid  = threadIdx.x;
    const int lane = tid & 63;
    const int wid  = tid >> 6;
    const int wr = wid >> 1, wc = wid & 1;
    const int g = lane >> 4, nn = lane & 15;

    const int r0 = tid >> 3;                       // 0..31
    const int sx = ((tid & 7) ^ (r0 & 7)) << 3;

    const ushort* Ap = &A[(size_t)(row0 + r0) * K + sx];
    const ushort* Wp = &Wt[(size_t)(col0 + r0) * K + sx];
    const size_t rstep = (size_t)32 * K;

    ushort* ldsA = sA + wid * 512;     // A buffer = 2048 ushorts (32 rows x 64)
    ushort* ldsW = sW + wid * 512;     // W buffer = 4096 ushorts (64 rows x 64)

    gload_lds16(Ap,         ldsA);
    gload_lds16(Wp,         ldsW);
    gload_lds16(Wp + rstep, ldsW + 2048);

    const int ra = (wr * 16 + nn) * 64;
    const int rc = (wc * 32 + nn) * 64, rd = rc + 16 * 64;
    const int m7 = nn & 7;

    int cur = 0;
    __syncthreads();
    for (int k0 = 0; k0 < K; k0 += 64) {
        if (k0 + 64 < K) {
            ushort* lA = ldsA + (cur ^ 1) * 2048;
            ushort* lW = ldsW + (cur ^ 1) * 4096;
            gload_lds16(Ap + k0 + 64,         lA);
            gload_lds16(Wp + k0 + 64,         lW);
            gload_lds16(Wp + k0 + 64 + rstep, lW + 2048);
        }
        const ushort* a = sA + cur * 2048;
        const ushort* w = sW + cur * 4096;
#pragma unroll
        for (int sk = 0; sk < 2; ++sk) {
            const int sw = ((sk * 4 + g) ^ m7) << 3;
            bf16x8 a0 = *reinterpret_cast<const bf16x8*>(&a[ra + sw]);
            bf16x8 w0 = *reinterpret_cast<const bf16x8*>(&w[rc + sw]);
            bf16x8 w1 = *reinterpret_cast<const bf16x8*>(&w[rd + sw]);
            acc[0] = __builtin_amdgcn_mfma_f32_16x16x32_bf16(a0, w0, acc[0], 0, 0, 0);
            acc[1] = __builtin_amdgcn_mfma_f32_16x16x32_bf16(a0, w1, acc[1], 0, 0, 0);
        }
        __syncthreads();
        cur ^= 1;
    }
}

// 32-tile GEMM + in-place fp32 residual (Wo / FF2). grid = (4, 128).
__global__ __launch_bounds__(256) void gemm_res32(
    const ushort* __restrict__ A, const ushort* __restrict__ Wt,
    const float* __restrict__ bias, float* __restrict__ C, int K)
{
    __shared__ __align__(16) ushort sA[2 * 2048];
    __shared__ __align__(16) ushort sW[2 * 4096];
    const int row0 = blockIdx.y * 32, col0 = blockIdx.x * 64;
    f32x4 acc[2] = {};
    gemm_core32(A, Wt, K, row0, col0, sA, sW, acc);

    const int lane = threadIdx.x & 63;
    const int wid  = threadIdx.x >> 6;
    const int wr = wid >> 1, wc = wid & 1;
    const int g = lane >> 4, nn = lane & 15;
#pragma unroll
    for (int ni = 0; ni < 2; ++ni)
#pragma unroll
    for (int r = 0; r < 4; ++r) {
        const int m = row0 + wr * 16 + g * 4 + r;
        const int c = col0 + wc * 32 + ni * 16 + nn;
        C[(size_t)m * D_ + c] += acc[ni][r] + bias[c];
    }
}

// 32-tile GEMM, fp32 out, no residual (first / final). K = 256, N = 256.
__global__ __launch_bounds__(256) void gemm_out32(
    const ushort* __restrict__ A, const ushort* __restrict__ Wt,
    const float* __restrict__ bias, float* __restrict__ Cout)
{
    __shared__ __align__(16) ushort sA[2 * 2048];
    __shared__ __align__(16) ushort sW[2 * 4096];
    const int row0 = blockIdx.y * 32, col0 = blockIdx.x * 64;
    f32x4 acc[2] = {};
    gemm_core32(A, Wt, 256, row0, col0, sA, sW, acc);

    const int lane = threadIdx.x & 63;
    const int wid  = threadIdx.x >> 6;
    const int wr = wid >> 1, wc = wid & 1;
    const int g = lane >> 4, nn = lane & 15;
#pragma unroll
    for (int ni = 0; ni < 2; ++ni)
#pragma unroll
    for (int r = 0; r < 4; ++r) {
        const int m = row0 + wr * 16 + g * 4 + r;
        const int c = col0 + wc * 32 + ni * 16 + nn;
        Cout[(size_t)m * D_ + c] = acc[ni][r] + bias[c];
    }
}

// ---------------------------------------------------------------------------
// Generic 64-tile GEMM + epilogue (FF1 GELU path). EPI: 1 exact GELU.
// ---------------------------------------------------------------------------
template<int EPI, int OUTBF>
__global__ __launch_bounds__(256) void gemm_bf16(
    const ushort* __restrict__ A, const ushort* __restrict__ Wt,
    const float* __restrict__ bias, const float* __restrict__ res,
    void* __restrict__ Cout, int M, int N, int K)
{
    __shared__ __align__(16) ushort sA[2 * 4096];
    __shared__ __align__(16) ushort sW[2 * 4096];
    const int row0 = blockIdx.y * 64, col0 = blockIdx.x * 64;
    f32x4 acc[2][2] = {};
    gemm_core64(A, Wt, K, row0, col0, sA, sW, acc);

    const int lane = threadIdx.x & 63;
    const int wid  = threadIdx.x >> 6;
    const int wr = wid >> 1, wc = wid & 1;
    const int g = lane >> 4, nn = lane & 15;
#pragma unroll
    for (int mi = 0; mi < 2; ++mi)
#pragma unroll
    for (int ni = 0; ni < 2; ++ni)
#pragma unroll
    for (int r = 0; r < 4; ++r) {
        const int m = row0 + wr * 32 + mi * 16 + g * 4 + r;
        const int c = col0 + wc * 32 + ni * 16 + nn;
        float v = acc[mi][ni][r] + bias[c];
        if (EPI == 1) v = 0.5f * v * (1.0f + erff(v * 0.70710678118654752f));
        if (EPI == 2) v += res[(size_t)m * N + c];
        if (OUTBF) ((ushort*)Cout)[(size_t)m * N + c] = (ushort)f2bf(v);
        else       ((float*)Cout)[(size_t)m * N + c] = v;
    }
}

// ---------------------------------------------------------------------------
// Fused QKV GEMM (round-6 verified; already 3 blocks/CU).
// ---------------------------------------------------------------------------
__global__ __launch_bounds__(256) void gemm_qkv(
    const ushort* __restrict__ A,
    const ushort* __restrict__ WqT, const ushort* __restrict__ WkT,
    const ushort* __restrict__ WvT,
    const float* __restrict__ bq, const float* __restrict__ bk,
    const float* __restrict__ bv,
    ushort* __restrict__ Qb, ushort* __restrict__ Kb, ushort* __restrict__ Vt)
{
    __shared__ __align__(16) ushort sA[2 * 4096];
    __shared__ __align__(16) ushort sW[2 * 4096];
    const int nb = blockIdx.x;
    const int wsel = nb >> 2;
    const int col0 = (nb & 3) * 64;
    const int row0 = blockIdx.y * 64;
    const ushort* Wt = (wsel == 0) ? WqT : (wsel == 1) ? WkT : WvT;
    const float* bias = (wsel == 0) ? bq : (wsel == 1) ? bk : bv;

    f32x4 acc[2][2] = {};
    gemm_core64(A, Wt, 256, row0, col0, sA, sW, acc);

    const int lane = threadIdx.x & 63;
    const int wid  = threadIdx.x >> 6;
    const int wr = wid >> 1, wc = wid & 1;
    const int g = lane >> 4, nn = lane & 15;
    ushort* QK = (wsel == 0) ? Qb : Kb;
#pragma unroll
    for (int mi = 0; mi < 2; ++mi)
#pragma unroll
    for (int ni = 0; ni < 2; ++ni)
#pragma unroll
    for (int r = 0; r < 4; ++r) {
        const int m = row0 + wr * 32 + mi * 16 + g * 4 + r;
        const int c = col0 + wc * 32 + ni * 16 + nn;
        const float v = acc[mi][ni][r] + bias[c];
        if (wsel < 2) {
            QK[(size_t)m * D_ + c] = (ushort)f2bf(v);
        } else {
            const int b = m >> 11, l = m & 2047;
            const int h = c >> 5,  d = c & 31;
            Vt[(size_t)((b * 8 + h) * 32 + d) * L_ + l] = (ushort)f2bf(v);
        }
    }
}

// ---------------------------------------------------------------------------
// LayerNorm over D=256 -> bf16 out. One block per row.  (round-6 verified)
// ---------------------------------------------------------------------------
__global__ __launch_bounds__(256) void ln_kernel(
    const float* __restrict__ x, const float* __restrict__ g,
    const float* __restrict__ b, ushort* __restrict__ y)
{
    const int row = blockIdx.x;
    const int tid = threadIdx.x;
    const float v = x[row * D_ + tid];
    float s = v, s2 = v * v;
#pragma unroll
    for (int off = 32; off > 0; off >>= 1) {
        s  += __shfl_xor(s,  off);
        s2 += __shfl_xor(s2, off);
    }
    __shared__ float ls[4], ls2[4];
    const int wid = tid >> 6;
    if ((tid & 63) == 0) { ls[wid] = s; ls2[wid] = s2; }
    __syncthreads();
    s  = ls[0]  + ls[1]  + ls[2]  + ls[3];
    s2 = ls2[0] + ls2[1] + ls2[2] + ls2[3];
    const float m   = s * (1.0f / D_);
    const float var = s2 * (1.0f / D_) - m * m;
    const float r   = rsqrtf(var + 1e-5f);
    y[row * D_ + tid] = (ushort)f2bf((v - m) * r * g[tid] + b[tid]);
}

// ---------------------------------------------------------------------------
// MFMA evidence attention v7 (round-12 verified): depth-2 K/V prefetch,
// parity-static register slots, fused uncertainty finalize.
// ---------------------------------------------------------------------------
__global__ __launch_bounds__(256) void attn_mfma(
    const ushort* __restrict__ Qb, const ushort* __restrict__ Kb,
    const ushort* __restrict__ Vt, ushort* __restrict__ O,
    float* __restrict__ unc, const float* __restrict__ ev_scale,
    const float* __restrict__ ev_bias, int layer,
    float* __restrict__ out_unc, float* __restrict__ out_abst)
{
    const int bh = blockIdx.y;
    const int b  = bh >> 3;
    const int h  = bh & 7;
    const int tid  = threadIdx.x;
    const int wv   = tid >> 6;
    const int lane = tid & 63;
    const int g = lane >> 4;
    const int n = lane & 15;
    const int q  = blockIdx.x * 64 + wv * 16 + n;
    const float scale = ev_scale[layer];
    const float cb    = 1.0f + ev_bias[layer];
    const float isq   = 0.17677669529663687f;   // 1/sqrt(32)

    __shared__ __align__(16) ushort sK[2][64][40];
    __shared__ __align__(16) ushort sV[2][32][72];

    const size_t qk0 = (size_t)b * L_ * D_ + h * HD_;

    bf16x8 qf;
    {
        const bf16x8 qr = *reinterpret_cast<const bf16x8*>(&Qb[qk0 + (size_t)q * D_ + g * 8]);
#pragma unroll
        for (int j = 0; j < 8; ++j) {
            const float qv = __builtin_bit_cast(float, ((unsigned)(unsigned short)qr[j]) << 16);
            qf[j] = f2bf(qv * isq);
        }
    }
    bf16x8 ones;
#pragma unroll
    for (int j = 0; j < 8; ++j) ones[j] = (short)0x3F80;

    const int krow = tid >> 2, kch = (tid & 3) * 8;
    const int vrow = tid >> 3, vch = (tid & 7) * 8;
    const ushort* ksrc = Kb + qk0 + (size_t)krow * D_ + kch;
    const ushort* vsrc = Vt + (size_t)((b * 8 + h) * 32 + vrow) * L_ + vch;

    f32x4 acc0 = {0.f, 0.f, 0.f, 0.f};
    f32x4 acc1 = {0.f, 0.f, 0.f, 0.f};
    f32x4 accS = {0.f, 0.f, 0.f, 0.f};
    const f32x4 zero = {0.f, 0.f, 0.f, 0.f};

    bf16x8 kA = *reinterpret_cast<const bf16x8*>(ksrc);
    bf16x8 vA = *reinterpret_cast<const bf16x8*>(vsrc);
    bf16x8 kB = *reinterpret_cast<const bf16x8*>(ksrc + (size_t)64 * D_);
    bf16x8 vB = *reinterpret_cast<const bf16x8*>(vsrc + 64);

#define ATTN_TILE(BUF)                                                          \
    do {                                                                        \
        _Pragma("unroll")                                                       \
        for (int tt = 0; tt < 64; tt += 32) {                                   \
            bf16x8 kf0 = *reinterpret_cast<const bf16x8*>(&sK[BUF][tt + n][g * 8]);      \
            bf16x8 kf1 = *reinterpret_cast<const bf16x8*>(&sK[BUF][tt + 16 + n][g * 8]); \
            f32x4 s0 = __builtin_amdgcn_mfma_f32_16x16x32_bf16(kf0, qf, zero, 0, 0, 0);  \
            f32x4 s1 = __builtin_amdgcn_mfma_f32_16x16x32_bf16(kf1, qf, zero, 0, 0, 0);  \
            short4 va = *reinterpret_cast<const short4*>(&sV[BUF][n][tt + g * 4]);       \
            short4 vb = *reinterpret_cast<const short4*>(&sV[BUF][n][tt + 16 + g * 4]);  \
            short4 vc = *reinterpret_cast<const short4*>(&sV[BUF][n + 16][tt + g * 4]);  \
            short4 vd = *reinterpret_cast<const short4*>(&sV[BUF][n + 16][tt + 16 + g * 4]); \
            bf16x8 vf0 = {va.x, va.y, va.z, va.w, vb.x, vb.y, vb.z, vb.w};      \
            bf16x8 vf1 = {vc.x, vc.y, vc.z, vc.w, vd.x, vd.y, vd.z, vd.w};      \
            bf16x8 pa;                                                          \
            _Pragma("unroll")                                                   \
            for (int r = 0; r < 4; ++r) pa[r]     = f2bf(fmaf(__expf(s0[r]), scale, cb)); \
            _Pragma("unroll")                                                   \
            for (int r = 0; r < 4; ++r) pa[r + 4] = f2bf(fmaf(__expf(s1[r]), scale, cb)); \
            acc0 = __builtin_amdgcn_mfma_f32_16x16x32_bf16(vf0, pa, acc0, 0, 0, 0); \
            acc1 = __builtin_amdgcn_mfma_f32_16x16x32_bf16(vf1, pa, acc1, 0, 0, 0); \
            accS = __builtin_amdgcn_mfma_f32_16x16x32_bf16(ones, pa, accS, 0, 0, 0); \
        }                                                                       \
    } while (0)

    for (int t = 0; t < L_; t += 128) {
        *reinterpret_cast<bf16x8*>(&sK[0][krow][kch]) = kA;
        *reinterpret_cast<bf16x8*>(&sV[0][vrow][vch]) = vA;
        if (t + 128 < L_) {
            kA = *reinterpret_cast<const bf16x8*>(ksrc + (size_t)(t + 128) * D_);
            vA = *reinterpret_cast<const bf16x8*>(vsrc + (t + 128));
        }
        __syncthreads();
        ATTN_TILE(0);

        *reinterpret_cast<bf16x8*>(&sK[1][krow][kch]) = kB;
        *reinterpret_cast<bf16x8*>(&sV[1][vrow][vch]) = vB;
        if (t + 192 < L_) {
            kB = *reinterpret_cast<const bf16x8*>(ksrc + (size_t)(t + 192) * D_);
            vB = *reinterpret_cast<const bf16x8*>(vsrc + (t + 192));
        }
        __syncthreads();
        ATTN_TILE(1);
    }
#undef ATTN_TILE

    const float inv = 1.0f / accS[0];

    ushort* op = &O[qk0 + (size_t)q * D_ + g * 4];
    short4 o0 = {f2bf(acc0[0] * inv), f2bf(acc0[1] * inv), f2bf(acc0[2] * inv), f2bf(acc0[3] * inv)};
    short4 o1 = {f2bf(acc1[0] * inv), f2bf(acc1[1] * inv), f2bf(acc1[2] * inv), f2bf(acc1[3] * inv)};
    *reinterpret_cast<short4*>(op)      = o0;
    *reinterpret_cast<short4*>(op + 16) = o1;

    if (g == 0) {
        const float u = (float)L_ * inv;
        const int uidx = bh * L_ + q;
        if (layer == 0) {
            unc[uidx] = u;                      // '=' : deterministic across replays
        } else if (layer < LY_ - 1) {
            unc[uidx] += u;
        } else {
            const float avg = (unc[uidx] + u) * 0.25f;
            out_unc[uidx]  = avg;
            out_abst[uidx] = (avg > 0.3f) ? 1.0f : 0.0f;
        }
    }
}

// ---------------------------------------------------------------------------
extern "C" void kernel_launch(void* const* d_in, const int* in_sizes, int n_in,
                              void* d_out, int out_size, void* d_ws, size_t ws_size,
                              hipStream_t stream)
{
    const float* x    = (const float*)d_in[0];
    const float* Win  = (const float*)d_in[1];
    const float* bin_ = (const float*)d_in[2];
    const float* Wq   = (const float*)d_in[3];
    const float* bq   = (const float*)d_in[4];
    const float* Wk   = (const float*)d_in[5];
    const float* bk   = (const float*)d_in[6];
    const float* Wv   = (const float*)d_in[7];
    const float* bv   = (const float*)d_in[8];
    const float* Wo   = (const float*)d_in[9];
    const float* bo   = (const float*)d_in[10];
    const float* evs  = (const float*)d_in[11];
    const float* evb  = (const float*)d_in[12];
    const float* W1   = (const float*)d_in[13];
    const float* b1   = (const float*)d_in[14];
    const float* W2   = (const float*)d_in[15];
    const float* b2   = (const float*)d_in[16];
    const float* n1g  = (const float*)d_in[17];
    const float* n1b  = (const float*)d_in[18];
    const float* n2g  = (const float*)d_in[19];
    const float* n2b  = (const float*)d_in[20];
    const float* fng  = (const float*)d_in[21];
    const float* fnb  = (const float*)d_in[22];
    const float* Wout = (const float*)d_in[23];
    const float* bout = (const float*)d_in[24];

    char* ws = (char*)d_ws;
    float*  h    = (float*) (ws);                  // 4 MB fp32 residual stream
    ushort* tmpb = (ushort*)(ws + (4  << 20));     // 2 MB bf16 (LN out / x-bf16)
    ushort* Qb   = (ushort*)(ws + (6  << 20));     // 2 MB
    ushort* Kb   = (ushort*)(ws + (8  << 20));     // 2 MB
    ushort* Vt   = (ushort*)(ws + (10 << 20));     // 2 MB (transposed V)
    ushort* Ob   = (ushort*)(ws + (12 << 20));     // 2 MB (attn out)
    ushort* ffb  = (ushort*)(ws + (6  << 20));     // 8 MB, overlays Qb..Ob (dead by FF1)
    float*  unc  = (float*) (ws + (14 << 20));     // 128 KB
    ushort* T    = (ushort*)(ws + (15 << 20));     // 6.55 MB transposed bf16 weights

    ushort* winT  = T;
    ushort* woutT = T + 65536 * 17 + 2097152;

    float* out_main = (float*)d_out;
    float* out_unc  = out_main + M_ * D_;
    float* out_abst = out_unc + B_ * H_ * L_;

    const dim3 blk(256);
    const dim3 g32(4, 128);     // 32x64-tile GEMMs (2 blocks/CU)
    const dim3 g1024(16, 64);   // N=1024 GEMM
    const dim3 gqkv(12, 64);
    const dim3 gattn(L_ / 64, B_ * H_);

    transpose_weights<<<3200, blk, 0, stream>>>(Win, Wq, Wk, Wv, Wo, W1, W2, Wout, T);
    f32_to_bf16<<<1024, blk, 0, stream>>>(x, tmpb);
    gemm_out32<<<g32, blk, 0, stream>>>(tmpb, winT, bin_, h);

    for (int i = 0; i < LY_; ++i) {
        ushort* wqT = T + 65536 * (1 + i);
        ushort* wkT = T + 65536 * (5 + i);
        ushort* wvT = T + 65536 * (9 + i);
        ushort* woT = T + 65536 * (13 + i);
        ushort* w1T = T + 65536 * 17 + i * 262144;
        ushort* w2T = T + 65536 * 17 + 1048576 + i * 262144;

        ln_kernel<<<M_, blk, 0, stream>>>(h, n1g + i * D_, n1b + i * D_, tmpb);
        gemm_qkv<<<gqkv, blk, 0, stream>>>(tmpb, wqT, wkT, wvT,
                                           bq + i * D_, bk + i * D_, bv + i * D_,
                                           Qb, Kb, Vt);
        attn_mfma<<<gattn, blk, 0, stream>>>(Qb, Kb, Vt, Ob, unc, evs, evb, i,
                                             out_unc, out_abst);
        gemm_res32<<<g32, blk, 0, stream>>>(Ob, woT, bo + i * D_, h, 256);
        ln_kernel<<<M_, blk, 0, stream>>>(h, n2g + i * D_, n2b + i * D_, tmpb);
        gemm_bf16<1, 1><<<g1024, blk, 0, stream>>>(tmpb, w1T, b1 + i * F_, nullptr, ffb, M_, F_, D_);
        gemm_res32<<<g32, blk, 0, stream>>>(ffb, w2T, b2 + i * D_, h, 1024);
    }

    ln_kernel<<<M_, blk, 0, stream>>>(h, fng, fnb, tmpb);
    gemm_out32<<<g32, blk, 0, stream>>>(tmpb, woutT, bout, out_main);
}

// Round 14
// 284.080 us; speedup vs baseline: 1.0544x; 1.0544x over previous
//
#include <hip/hip_runtime.h>
#include <hip/hip_bf16.h>
#include <math.h>

#define B_  2
#define L_  2048
#define D_  256
#define H_  8
#define HD_ 32
#define F_  1024
#define LY_ 4
#define M_  (B_*L_)

typedef __attribute__((ext_vector_type(8))) short bf16x8;   // 8 bf16 in 4 VGPRs
typedef __attribute__((ext_vector_type(4))) float f32x4;

static __device__ __forceinline__ short f2bf(float f) {
    return __builtin_bit_cast(short, __float2bfloat16(f));
}

static __device__ __forceinline__ void gload_lds16(const ushort* g, ushort* l) {
    __builtin_amdgcn_global_load_lds(
        (const __attribute__((address_space(1))) void*)g,
        (__attribute__((address_space(3))) void*)l, 16, 0, 0);
}

// ---------------------------------------------------------------------------
// Weight transpose + fp32->bf16:  W[K][N] -> Wt[N][K] bf16  (round-6 verified)
// ---------------------------------------------------------------------------
__global__ __launch_bounds__(256) void transpose_weights(
    const float* __restrict__ Win, const float* __restrict__ Wq,
    const float* __restrict__ Wk,  const float* __restrict__ Wv,
    const float* __restrict__ Wo,  const float* __restrict__ W1,
    const float* __restrict__ W2,  const float* __restrict__ Wout,
    ushort* __restrict__ T)
{
    const int bid = blockIdx.x;
    const float* src; ushort* dst; int K, N, tt;
    if (bid < 64)        { src = Win; dst = T; K = 256; N = 256; tt = bid; }
    else if (bid < 1088) {
        int i = bid - 64; int which = i >> 8; int l = (i >> 6) & 3; tt = i & 63;
        K = 256; N = 256;
        const float* s4[4] = {Wq, Wk, Wv, Wo};
        src = s4[which] + l * 65536;
        dst = T + 65536 * (1 + which * 4 + l);
    } else if (bid < 2112) {
        int i = bid - 1088; int l = i >> 8; tt = i & 255; K = 256; N = 1024;
        src = W1 + l * 262144; dst = T + 65536 * 17 + l * 262144;
    } else if (bid < 3136) {
        int i = bid - 2112; int l = i >> 8; tt = i & 255; K = 1024; N = 256;
        src = W2 + l * 262144; dst = T + 65536 * 17 + 1048576 + l * 262144;
    } else {
        src = Wout; dst = T + 65536 * 17 + 2097152; K = 256; N = 256; tt = bid - 3136;
    }
    const int ntn = N >> 5;
    const int tk = tt / ntn, tn = tt % ntn;
    __shared__ float ld[32][33];
    const int t = threadIdx.x;
    const int r = t >> 3, c4 = (t & 7) * 4;
    float4 v = *reinterpret_cast<const float4*>(&src[(size_t)(tk * 32 + r) * N + tn * 32 + c4]);
    ld[r][c4 + 0] = v.x; ld[r][c4 + 1] = v.y; ld[r][c4 + 2] = v.z; ld[r][c4 + 3] = v.w;
    __syncthreads();
    short4 o;
    o.x = f2bf(ld[c4 + 0][r]);
    o.y = f2bf(ld[c4 + 1][r]);
    o.z = f2bf(ld[c4 + 2][r]);
    o.w = f2bf(ld[c4 + 3][r]);
    *reinterpret_cast<short4*>(&dst[(size_t)(tn * 32 + r) * K + tk * 32 + c4]) = o;
}

// ---------------------------------------------------------------------------
// bf16 MFMA GEMM core v2 (round-6 verified, 64x64 tile).
// ---------------------------------------------------------------------------
__device__ __forceinline__ void gemm_core64(
    const ushort* __restrict__ A, const ushort* __restrict__ Wt, int K,
    int row0, int col0, ushort* sA, ushort* sW, f32x4 acc[2][2])
{
    const int tid  = threadIdx.x;
    const int lane = tid & 63;
    const int wid  = tid >> 6;
    const int wr = wid >> 1, wc = wid & 1;
    const int g = lane >> 4, nn = lane & 15;

    const int r0 = tid >> 3;
    const int sx = ((tid & 7) ^ (r0 & 7)) << 3;

    const ushort* Ap = &A[(size_t)(row0 + r0) * K + sx];
    const ushort* Wp = &Wt[(size_t)(col0 + r0) * K + sx];
    const size_t rstep = (size_t)32 * K;

    ushort* ldsA = sA + wid * 512;
    ushort* ldsW = sW + wid * 512;

    gload_lds16(Ap,         ldsA);
    gload_lds16(Ap + rstep, ldsA + 2048);
    gload_lds16(Wp,         ldsW);
    gload_lds16(Wp + rstep, ldsW + 2048);

    const int ra = (wr * 32 + nn) * 64, rb = ra + 16 * 64;
    const int rc = (wc * 32 + nn) * 64, rd = rc + 16 * 64;
    const int m7 = nn & 7;

    int cur = 0;
    __syncthreads();
    for (int k0 = 0; k0 < K; k0 += 64) {
        if (k0 + 64 < K) {
            ushort* lA = ldsA + (cur ^ 1) * 4096;
            ushort* lW = ldsW + (cur ^ 1) * 4096;
            gload_lds16(Ap + k0 + 64,         lA);
            gload_lds16(Ap + k0 + 64 + rstep, lA + 2048);
            gload_lds16(Wp + k0 + 64,         lW);
            gload_lds16(Wp + k0 + 64 + rstep, lW + 2048);
        }
        const ushort* a = sA + cur * 4096;
        const ushort* w = sW + cur * 4096;
#pragma unroll
        for (int sk = 0; sk < 2; ++sk) {
            const int sw = ((sk * 4 + g) ^ m7) << 3;
            bf16x8 a0 = *reinterpret_cast<const bf16x8*>(&a[ra + sw]);
            bf16x8 a1 = *reinterpret_cast<const bf16x8*>(&a[rb + sw]);
            bf16x8 w0 = *reinterpret_cast<const bf16x8*>(&w[rc + sw]);
            bf16x8 w1 = *reinterpret_cast<const bf16x8*>(&w[rd + sw]);
            acc[0][0] = __builtin_amdgcn_mfma_f32_16x16x32_bf16(a0, w0, acc[0][0], 0, 0, 0);
            acc[0][1] = __builtin_amdgcn_mfma_f32_16x16x32_bf16(a0, w1, acc[0][1], 0, 0, 0);
            acc[1][0] = __builtin_amdgcn_mfma_f32_16x16x32_bf16(a1, w0, acc[1][0], 0, 0, 0);
            acc[1][1] = __builtin_amdgcn_mfma_f32_16x16x32_bf16(a1, w1, acc[1][1], 0, 0, 0);
        }
        __syncthreads();
        cur ^= 1;
    }
}

// ---------------------------------------------------------------------------
// First GEMM: x fp32 -> h fp32 with convert-only A prologue (round-10
// verified core_f<0> path, inlined).
// ---------------------------------------------------------------------------
__global__ __launch_bounds__(256) void gemm_first(
    const float* __restrict__ Hin, const ushort* __restrict__ Wt,
    const float* __restrict__ bias, float* __restrict__ Cout)
{
    __shared__ __align__(16) ushort sLN[64 * 264];
    __shared__ __align__(16) ushort sW[2 * 4096];
    const int row0 = blockIdx.y * 64, col0 = blockIdx.x * 64;
    const int tid  = threadIdx.x;
    const int lane = tid & 63;
    const int wid  = tid >> 6;
    const int wr = wid >> 1, wc = wid & 1;
    const int g = lane >> 4, nn = lane & 15;

    const int r0 = tid >> 3;
    const int sx = ((tid & 7) ^ (r0 & 7)) << 3;
    const ushort* Wp = &Wt[(size_t)(col0 + r0) * 256 + sx];
    ushort* ldsW = sW + wid * 512;
    gload_lds16(Wp,            ldsW);
    gload_lds16(Wp + 32 * 256, ldsW + 2048);

    const float4* hp = reinterpret_cast<const float4*>(Hin + (size_t)row0 * D_);
#pragma unroll
    for (int j = 0; j < 16; ++j) {
        const float4 v = hp[j * 256 + tid];
        short4 o = {f2bf(v.x), f2bf(v.y), f2bf(v.z), f2bf(v.w)};
        *reinterpret_cast<short4*>(&sLN[(j * 4 + wid) * 264 + lane * 4]) = o;
    }
    __syncthreads();

    const int ra = (wr * 32 + nn) * 264, rb = ra + 16 * 264;
    const int rc = (wc * 32 + nn) * 64,  rd = rc + 16 * 64;
    const int m7 = nn & 7;
    f32x4 acc[2][2] = {};

    int cur = 0;
#pragma unroll
    for (int k0 = 0; k0 < 256; k0 += 64) {
        if (k0 + 64 < 256) {
            ushort* lW = ldsW + (cur ^ 1) * 4096;
            gload_lds16(Wp + k0 + 64,            lW);
            gload_lds16(Wp + k0 + 64 + 32 * 256, lW + 2048);
        }
        const ushort* w = sW + cur * 4096;
#pragma unroll
        for (int sk = 0; sk < 2; ++sk) {
            const int ac = k0 + sk * 32 + g * 8;
            bf16x8 a0 = *reinterpret_cast<const bf16x8*>(&sLN[ra + ac]);
            bf16x8 a1 = *reinterpret_cast<const bf16x8*>(&sLN[rb + ac]);
            const int sw = ((sk * 4 + g) ^ m7) << 3;
            bf16x8 w0 = *reinterpret_cast<const bf16x8*>(&w[rc + sw]);
            bf16x8 w1 = *reinterpret_cast<const bf16x8*>(&w[rd + sw]);
            acc[0][0] = __builtin_amdgcn_mfma_f32_16x16x32_bf16(a0, w0, acc[0][0], 0, 0, 0);
            acc[0][1] = __builtin_amdgcn_mfma_f32_16x16x32_bf16(a0, w1, acc[0][1], 0, 0, 0);
            acc[1][0] = __builtin_amdgcn_mfma_f32_16x16x32_bf16(a1, w0, acc[1][0], 0, 0, 0);
            acc[1][1] = __builtin_amdgcn_mfma_f32_16x16x32_bf16(a1, w1, acc[1][1], 0, 0, 0);
        }
        __syncthreads();
        cur ^= 1;
    }

#pragma unroll
    for (int mi = 0; mi < 2; ++mi)
#pragma unroll
    for (int ni = 0; ni < 2; ++ni)
#pragma unroll
    for (int r = 0; r < 4; ++r) {
        const int m = row0 + wr * 32 + mi * 16 + g * 4 + r;
        const int c = col0 + wc * 32 + ni * 16 + nn;
        Cout[(size_t)m * D_ + c] = acc[mi][ni][r] + bias[c];
    }
}

// ---------------------------------------------------------------------------
// 32x64-tile core + residual GEMMs (round-13 verified).
// ---------------------------------------------------------------------------
__device__ __forceinline__ void gemm_core32(
    const ushort* __restrict__ A, const ushort* __restrict__ Wt, int K,
    int row0, int col0, ushort* sA, ushort* sW, f32x4 acc[2])
{
    const int tid  = threadIdx.x;
    const int lane = tid & 63;
    const int wid  = tid >> 6;
    const int wr = wid >> 1, wc = wid & 1;
    const int g = lane >> 4, nn = lane & 15;

    const int r0 = tid >> 3;
    const int sx = ((tid & 7) ^ (r0 & 7)) << 3;

    const ushort* Ap = &A[(size_t)(row0 + r0) * K + sx];
    const ushort* Wp = &Wt[(size_t)(col0 + r0) * K + sx];
    const size_t rstep = (size_t)32 * K;

    ushort* ldsA = sA + wid * 512;
    ushort* ldsW = sW + wid * 512;

    gload_lds16(Ap,         ldsA);
    gload_lds16(Wp,         ldsW);
    gload_lds16(Wp + rstep, ldsW + 2048);

    const int ra = (wr * 16 + nn) * 64;
    const int rc = (wc * 32 + nn) * 64, rd = rc + 16 * 64;
    const int m7 = nn & 7;

    int cur = 0;
    __syncthreads();
    for (int k0 = 0; k0 < K; k0 += 64) {
        if (k0 + 64 < K) {
            ushort* lA = ldsA + (cur ^ 1) * 2048;
            ushort* lW = ldsW + (cur ^ 1) * 4096;
            gload_lds16(Ap + k0 + 64,         lA);
            gload_lds16(Wp + k0 + 64,         lW);
            gload_lds16(Wp + k0 + 64 + rstep, lW + 2048);
        }
        const ushort* a = sA + cur * 2048;
        const ushort* w = sW + cur * 4096;
#pragma unroll
        for (int sk = 0; sk < 2; ++sk) {
            const int sw = ((sk * 4 + g) ^ m7) << 3;
            bf16x8 a0 = *reinterpret_cast<const bf16x8*>(&a[ra + sw]);
            bf16x8 w0 = *reinterpret_cast<const bf16x8*>(&w[rc + sw]);
            bf16x8 w1 = *reinterpret_cast<const bf16x8*>(&w[rd + sw]);
            acc[0] = __builtin_amdgcn_mfma_f32_16x16x32_bf16(a0, w0, acc[0], 0, 0, 0);
            acc[1] = __builtin_amdgcn_mfma_f32_16x16x32_bf16(a0, w1, acc[1], 0, 0, 0);
        }
        __syncthreads();
        cur ^= 1;
    }
}

__global__ __launch_bounds__(256) void gemm_res32(
    const ushort* __restrict__ A, const ushort* __restrict__ Wt,
    const float* __restrict__ bias, float* __restrict__ C, int K)
{
    __shared__ __align__(16) ushort sA[2 * 2048];
    __shared__ __align__(16) ushort sW[2 * 4096];
    const int row0 = blockIdx.y * 32, col0 = blockIdx.x * 64;
    f32x4 acc[2] = {};
    gemm_core32(A, Wt, K, row0, col0, sA, sW, acc);

    const int lane = threadIdx.x & 63;
    const int wid  = threadIdx.x >> 6;
    const int wr = wid >> 1, wc = wid & 1;
    const int g = lane >> 4, nn = lane & 15;
#pragma unroll
    for (int ni = 0; ni < 2; ++ni)
#pragma unroll
    for (int r = 0; r < 4; ++r) {
        const int m = row0 + wr * 16 + g * 4 + r;
        const int c = col0 + wc * 32 + ni * 16 + nn;
        C[(size_t)m * D_ + c] += acc[ni][r] + bias[c];
    }
}

__global__ __launch_bounds__(256) void gemm_out32(
    const ushort* __restrict__ A, const ushort* __restrict__ Wt,
    const float* __restrict__ bias, float* __restrict__ Cout)
{
    __shared__ __align__(16) ushort sA[2 * 2048];
    __shared__ __align__(16) ushort sW[2 * 4096];
    const int row0 = blockIdx.y * 32, col0 = blockIdx.x * 64;
    f32x4 acc[2] = {};
    gemm_core32(A, Wt, 256, row0, col0, sA, sW, acc);

    const int lane = threadIdx.x & 63;
    const int wid  = threadIdx.x >> 6;
    const int wr = wid >> 1, wc = wid & 1;
    const int g = lane >> 4, nn = lane & 15;
#pragma unroll
    for (int ni = 0; ni < 2; ++ni)
#pragma unroll
    for (int r = 0; r < 4; ++r) {
        const int m = row0 + wr * 16 + g * 4 + r;
        const int c = col0 + wc * 32 + ni * 16 + nn;
        Cout[(size_t)m * D_ + c] = acc[ni][r] + bias[c];
    }
}

// ---------------------------------------------------------------------------
// Generic 64-tile GEMM + epilogue (FF1 GELU path).
// ---------------------------------------------------------------------------
template<int EPI, int OUTBF>
__global__ __launch_bounds__(256) void gemm_bf16(
    const ushort* __restrict__ A, const ushort* __restrict__ Wt,
    const float* __restrict__ bias, const float* __restrict__ res,
    void* __restrict__ Cout, int M, int N, int K)
{
    __shared__ __align__(16) ushort sA[2 * 4096];
    __shared__ __align__(16) ushort sW[2 * 4096];
    const int row0 = blockIdx.y * 64, col0 = blockIdx.x * 64;
    f32x4 acc[2][2] = {};
    gemm_core64(A, Wt, K, row0, col0, sA, sW, acc);

    const int lane = threadIdx.x & 63;
    const int wid  = threadIdx.x >> 6;
    const int wr = wid >> 1, wc = wid & 1;
    const int g = lane >> 4, nn = lane & 15;
#pragma unroll
    for (int mi = 0; mi < 2; ++mi)
#pragma unroll
    for (int ni = 0; ni < 2; ++ni)
#pragma unroll
    for (int r = 0; r < 4; ++r) {
        const int m = row0 + wr * 32 + mi * 16 + g * 4 + r;
        const int c = col0 + wc * 32 + ni * 16 + nn;
        float v = acc[mi][ni][r] + bias[c];
        if (EPI == 1) v = 0.5f * v * (1.0f + erff(v * 0.70710678118654752f));
        if (EPI == 2) v += res[(size_t)m * N + c];
        if (OUTBF) ((ushort*)Cout)[(size_t)m * N + c] = (ushort)f2bf(v);
        else       ((float*)Cout)[(size_t)m * N + c] = v;
    }
}

// ---------------------------------------------------------------------------
// Fused QKV GEMM (round-6 verified).
// ---------------------------------------------------------------------------
__global__ __launch_bounds__(256) void gemm_qkv(
    const ushort* __restrict__ A,
    const ushort* __restrict__ WqT, const ushort* __restrict__ WkT,
    const ushort* __restrict__ WvT,
    const float* __restrict__ bq, const float* __restrict__ bk,
    const float* __restrict__ bv,
    ushort* __restrict__ Qb, ushort* __restrict__ Kb, ushort* __restrict__ Vt)
{
    __shared__ __align__(16) ushort sA[2 * 4096];
    __shared__ __align__(16) ushort sW[2 * 4096];
    const int nb = blockIdx.x;
    const int wsel = nb >> 2;
    const int col0 = (nb & 3) * 64;
    const int row0 = blockIdx.y * 64;
    const ushort* Wt = (wsel == 0) ? WqT : (wsel == 1) ? WkT : WvT;
    const float* bias = (wsel == 0) ? bq : (wsel == 1) ? bk : bv;

    f32x4 acc[2][2] = {};
    gemm_core64(A, Wt, 256, row0, col0, sA, sW, acc);

    const int lane = threadIdx.x & 63;
    const int wid  = threadIdx.x >> 6;
    const int wr = wid >> 1, wc = wid & 1;
    const int g = lane >> 4, nn = lane & 15;
    ushort* QK = (wsel == 0) ? Qb : Kb;
#pragma unroll
    for (int mi = 0; mi < 2; ++mi)
#pragma unroll
    for (int ni = 0; ni < 2; ++ni)
#pragma unroll
    for (int r = 0; r < 4; ++r) {
        const int m = row0 + wr * 32 + mi * 16 + g * 4 + r;
        const int c = col0 + wc * 32 + ni * 16 + nn;
        const float v = acc[mi][ni][r] + bias[c];
        if (wsel < 2) {
            QK[(size_t)m * D_ + c] = (ushort)f2bf(v);
        } else {
            const int b = m >> 11, l = m & 2047;
            const int h = c >> 5,  d = c & 31;
            Vt[(size_t)((b * 8 + h) * 32 + d) * L_ + l] = (ushort)f2bf(v);
        }
    }
}

// ---------------------------------------------------------------------------
// LayerNorm v2: 8 rows per block (grid 512), vectorized float4 loads
// (32 B/lane), 32-lane butterfly stats. Same formula; coalesced.
// ---------------------------------------------------------------------------
__global__ __launch_bounds__(256) void ln_kernel8(
    const float* __restrict__ x, const float* __restrict__ g,
    const float* __restrict__ b, ushort* __restrict__ y)
{
    const int tid  = threadIdx.x;
    const int row  = blockIdx.x * 8 + (tid >> 5);
    const int l    = tid & 31;               // lane within row group
    const float* xp = x + (size_t)row * D_ + l * 8;

    float4 v0 = *reinterpret_cast<const float4*>(xp);
    float4 v1 = *reinterpret_cast<const float4*>(xp + 4);

    float s  = v0.x + v0.y + v0.z + v0.w + v1.x + v1.y + v1.z + v1.w;
    float s2 = v0.x*v0.x + v0.y*v0.y + v0.z*v0.z + v0.w*v0.w
             + v1.x*v1.x + v1.y*v1.y + v1.z*v1.z + v1.w*v1.w;
    s  += __shfl_xor(s, 1);  s  += __shfl_xor(s, 2);  s  += __shfl_xor(s, 4);
    s  += __shfl_xor(s, 8);  s  += __shfl_xor(s, 16);
    s2 += __shfl_xor(s2, 1); s2 += __shfl_xor(s2, 2); s2 += __shfl_xor(s2, 4);
    s2 += __shfl_xor(s2, 8); s2 += __shfl_xor(s2, 16);

    const float m   = s * (1.0f / D_);
    const float var = s2 * (1.0f / D_) - m * m;
    const float r   = rsqrtf(var + 1e-5f);

    const float4 g0 = reinterpret_cast<const float4*>(g)[l * 2];
    const float4 g1 = reinterpret_cast<const float4*>(g)[l * 2 + 1];
    const float4 b0 = reinterpret_cast<const float4*>(b)[l * 2];
    const float4 b1 = reinterpret_cast<const float4*>(b)[l * 2 + 1];

    short4 o0, o1;
    o0.x = f2bf((v0.x - m) * r * g0.x + b0.x);
    o0.y = f2bf((v0.y - m) * r * g0.y + b0.y);
    o0.z = f2bf((v0.z - m) * r * g0.z + b0.z);
    o0.w = f2bf((v0.w - m) * r * g0.w + b0.w);
    o1.x = f2bf((v1.x - m) * r * g1.x + b1.x);
    o1.y = f2bf((v1.y - m) * r * g1.y + b1.y);
    o1.z = f2bf((v1.z - m) * r * g1.z + b1.z);
    o1.w = f2bf((v1.w - m) * r * g1.w + b1.w);
    ushort* yp = y + (size_t)row * D_ + l * 8;
    *reinterpret_cast<short4*>(yp)     = o0;
    *reinterpret_cast<short4*>(yp + 4) = o1;
}

// ---------------------------------------------------------------------------
// MFMA evidence attention v7 (round-12 verified): depth-2 K/V prefetch,
// parity-static register slots, fused uncertainty finalize.
// ---------------------------------------------------------------------------
__global__ __launch_bounds__(256) void attn_mfma(
    const ushort* __restrict__ Qb, const ushort* __restrict__ Kb,
    const ushort* __restrict__ Vt, ushort* __restrict__ O,
    float* __restrict__ unc, const float* __restrict__ ev_scale,
    const float* __restrict__ ev_bias, int layer,
    float* __restrict__ out_unc, float* __restrict__ out_abst)
{
    const int bh = blockIdx.y;
    const int b  = bh >> 3;
    const int h  = bh & 7;
    const int tid  = threadIdx.x;
    const int wv   = tid >> 6;
    const int lane = tid & 63;
    const int g = lane >> 4;
    const int n = lane & 15;
    const int q  = blockIdx.x * 64 + wv * 16 + n;
    const float scale = ev_scale[layer];
    const float cb    = 1.0f + ev_bias[layer];
    const float isq   = 0.17677669529663687f;   // 1/sqrt(32)

    __shared__ __align__(16) ushort sK[2][64][40];
    __shared__ __align__(16) ushort sV[2][32][72];

    const size_t qk0 = (size_t)b * L_ * D_ + h * HD_;

    bf16x8 qf;
    {
        const bf16x8 qr = *reinterpret_cast<const bf16x8*>(&Qb[qk0 + (size_t)q * D_ + g * 8]);
#pragma unroll
        for (int j = 0; j < 8; ++j) {
            const float qv = __builtin_bit_cast(float, ((unsigned)(unsigned short)qr[j]) << 16);
            qf[j] = f2bf(qv * isq);
        }
    }
    bf16x8 ones;
#pragma unroll
    for (int j = 0; j < 8; ++j) ones[j] = (short)0x3F80;

    const int krow = tid >> 2, kch = (tid & 3) * 8;
    const int vrow = tid >> 3, vch = (tid & 7) * 8;
    const ushort* ksrc = Kb + qk0 + (size_t)krow * D_ + kch;
    const ushort* vsrc = Vt + (size_t)((b * 8 + h) * 32 + vrow) * L_ + vch;

    f32x4 acc0 = {0.f, 0.f, 0.f, 0.f};
    f32x4 acc1 = {0.f, 0.f, 0.f, 0.f};
    f32x4 accS = {0.f, 0.f, 0.f, 0.f};
    const f32x4 zero = {0.f, 0.f, 0.f, 0.f};

    bf16x8 kA = *reinterpret_cast<const bf16x8*>(ksrc);
    bf16x8 vA = *reinterpret_cast<const bf16x8*>(vsrc);
    bf16x8 kB = *reinterpret_cast<const bf16x8*>(ksrc + (size_t)64 * D_);
    bf16x8 vB = *reinterpret_cast<const bf16x8*>(vsrc + 64);

#define ATTN_TILE(BUF)                                                          \
    do {                                                                        \
        _Pragma("unroll")                                                       \
        for (int tt = 0; tt < 64; tt += 32) {                                   \
            bf16x8 kf0 = *reinterpret_cast<const bf16x8*>(&sK[BUF][tt + n][g * 8]);      \
            bf16x8 kf1 = *reinterpret_cast<const bf16x8*>(&sK[BUF][tt + 16 + n][g * 8]); \
            f32x4 s0 = __builtin_amdgcn_mfma_f32_16x16x32_bf16(kf0, qf, zero, 0, 0, 0);  \
            f32x4 s1 = __builtin_amdgcn_mfma_f32_16x16x32_bf16(kf1, qf, zero, 0, 0, 0);  \
            short4 va = *reinterpret_cast<const short4*>(&sV[BUF][n][tt + g * 4]);       \
            short4 vb = *reinterpret_cast<const short4*>(&sV[BUF][n][tt + 16 + g * 4]);  \
            short4 vc = *reinterpret_cast<const short4*>(&sV[BUF][n + 16][tt + g * 4]);  \
            short4 vd = *reinterpret_cast<const short4*>(&sV[BUF][n + 16][tt + 16 + g * 4]); \
            bf16x8 vf0 = {va.x, va.y, va.z, va.w, vb.x, vb.y, vb.z, vb.w};      \
            bf16x8 vf1 = {vc.x, vc.y, vc.z, vc.w, vd.x, vd.y, vd.z, vd.w};      \
            bf16x8 pa;                                                          \
            _Pragma("unroll")                                                   \
            for (int r = 0; r < 4; ++r) pa[r]     = f2bf(fmaf(__expf(s0[r]), scale, cb)); \
            _Pragma("unroll")                                                   \
            for (int r = 0; r < 4; ++r) pa[r + 4] = f2bf(fmaf(__expf(s1[r]), scale, cb)); \
            acc0 = __builtin_amdgcn_mfma_f32_16x16x32_bf16(vf0, pa, acc0, 0, 0, 0); \
            acc1 = __builtin_amdgcn_mfma_f32_16x16x32_bf16(vf1, pa, acc1, 0, 0, 0); \
            accS = __builtin_amdgcn_mfma_f32_16x16x32_bf16(ones, pa, accS, 0, 0, 0); \
        }                                                                       \
    } while (0)

    for (int t = 0; t < L_; t += 128) {
        *reinterpret_cast<bf16x8*>(&sK[0][krow][kch]) = kA;
        *reinterpret_cast<bf16x8*>(&sV[0][vrow][vch]) = vA;
        if (t + 128 < L_) {
            kA = *reinterpret_cast<const bf16x8*>(ksrc + (size_t)(t + 128) * D_);
            vA = *reinterpret_cast<const bf16x8*>(vsrc + (t + 128));
        }
        __syncthreads();
        ATTN_TILE(0);

        *reinterpret_cast<bf16x8*>(&sK[1][krow][kch]) = kB;
        *reinterpret_cast<bf16x8*>(&sV[1][vrow][vch]) = vB;
        if (t + 192 < L_) {
            kB = *reinterpret_cast<const bf16x8*>(ksrc + (size_t)(t + 192) * D_);
            vB = *reinterpret_cast<const bf16x8*>(vsrc + (t + 192));
        }
        __syncthreads();
        ATTN_TILE(1);
    }
#undef ATTN_TILE

    const float inv = 1.0f / accS[0];

    ushort* op = &O[qk0 + (size_t)q * D_ + g * 4];
    short4 o0 = {f2bf(acc0[0] * inv), f2bf(acc0[1] * inv), f2bf(acc0[2] * inv), f2bf(acc0[3] * inv)};
    short4 o1 = {f2bf(acc1[0] * inv), f2bf(acc1[1] * inv), f2bf(acc1[2] * inv), f2bf(acc1[3] * inv)};
    *reinterpret_cast<short4*>(op)      = o0;
    *reinterpret_cast<short4*>(op + 16) = o1;

    if (g == 0) {
        const float u = (float)L_ * inv;
        const int uidx = bh * L_ + q;
        if (layer == 0) {
            unc[uidx] = u;                      // '=' : deterministic across replays
        } else if (layer < LY_ - 1) {
            unc[uidx] += u;
        } else {
            const float avg = (unc[uidx] + u) * 0.25f;
            out_unc[uidx]  = avg;
            out_abst[uidx] = (avg > 0.3f) ? 1.0f : 0.0f;
        }
    }
}

// ---------------------------------------------------------------------------
extern "C" void kernel_launch(void* const* d_in, const int* in_sizes, int n_in,
                              void* d_out, int out_size, void* d_ws, size_t ws_size,
                              hipStream_t stream)
{
    const float* x    = (const float*)d_in[0];
    const float* Win  = (const float*)d_in[1];
    const float* bin_ = (const float*)d_in[2];
    const float* Wq   = (const float*)d_in[3];
    const float* bq   = (const float*)d_in[4];
    const float* Wk   = (const float*)d_in[5];
    const float* bk   = (const float*)d_in[6];
    const float* Wv   = (const float*)d_in[7];
    const float* bv   = (const float*)d_in[8];
    const float* Wo   = (const float*)d_in[9];
    const float* bo   = (const float*)d_in[10];
    const float* evs  = (const float*)d_in[11];
    const float* evb  = (const float*)d_in[12];
    const float* W1   = (const float*)d_in[13];
    const float* b1   = (const float*)d_in[14];
    const float* W2   = (const float*)d_in[15];
    const float* b2   = (const float*)d_in[16];
    const float* n1g  = (const float*)d_in[17];
    const float* n1b  = (const float*)d_in[18];
    const float* n2g  = (const float*)d_in[19];
    const float* n2b  = (const float*)d_in[20];
    const float* fng  = (const float*)d_in[21];
    const float* fnb  = (const float*)d_in[22];
    const float* Wout = (const float*)d_in[23];
    const float* bout = (const float*)d_in[24];

    char* ws = (char*)d_ws;
    float*  h    = (float*) (ws);                  // 4 MB fp32 residual stream
    ushort* tmpb = (ushort*)(ws + (4  << 20));     // 2 MB bf16 (LN out)
    ushort* Qb   = (ushort*)(ws + (6  << 20));     // 2 MB
    ushort* Kb   = (ushort*)(ws + (8  << 20));     // 2 MB
    ushort* Vt   = (ushort*)(ws + (10 << 20));     // 2 MB (transposed V)
    ushort* Ob   = (ushort*)(ws + (12 << 20));     // 2 MB (attn out)
    ushort* ffb  = (ushort*)(ws + (6  << 20));     // 8 MB, overlays Qb..Ob (dead by FF1)
    float*  unc  = (float*) (ws + (14 << 20));     // 128 KB
    ushort* T    = (ushort*)(ws + (15 << 20));     // 6.55 MB transposed bf16 weights

    ushort* winT  = T;
    ushort* woutT = T + 65536 * 17 + 2097152;

    float* out_main = (float*)d_out;
    float* out_unc  = out_main + M_ * D_;
    float* out_abst = out_unc + B_ * H_ * L_;

    const dim3 blk(256);
    const dim3 g64(4, 64);      // 64-tile GEMMs
    const dim3 g32(4, 128);     // 32x64-tile GEMMs (2 blocks/CU)
    const dim3 g1024(16, 64);   // N=1024 GEMM
    const dim3 gqkv(12, 64);
    const dim3 gattn(L_ / 64, B_ * H_);
    const dim3 gln(M_ / 8);

    transpose_weights<<<3200, blk, 0, stream>>>(Win, Wq, Wk, Wv, Wo, W1, W2, Wout, T);
    gemm_first<<<g64, blk, 0, stream>>>(x, winT, bin_, h);

    for (int i = 0; i < LY_; ++i) {
        ushort* wqT = T + 65536 * (1 + i);
        ushort* wkT = T + 65536 * (5 + i);
        ushort* wvT = T + 65536 * (9 + i);
        ushort* woT = T + 65536 * (13 + i);
        ushort* w1T = T + 65536 * 17 + i * 262144;
        ushort* w2T = T + 65536 * 17 + 1048576 + i * 262144;

        ln_kernel8<<<gln, blk, 0, stream>>>(h, n1g + i * D_, n1b + i * D_, tmpb);
        gemm_qkv<<<gqkv, blk, 0, stream>>>(tmpb, wqT, wkT, wvT,
                                           bq + i * D_, bk + i * D_, bv + i * D_,
                                           Qb, Kb, Vt);
        attn_mfma<<<gattn, blk, 0, stream>>>(Qb, Kb, Vt, Ob, unc, evs, evb, i,
                                             out_unc, out_abst);
        gemm_res32<<<g32, blk, 0, stream>>>(Ob, woT, bo + i * D_, h, 256);
        ln_kernel8<<<gln, blk, 0, stream>>>(h, n2g + i * D_, n2b + i * D_, tmpb);
        gemm_bf16<1, 1><<<g1024, blk, 0, stream>>>(tmpb, w1T, b1 + i * F_, nullptr, ffb, M_, F_, D_);
        gemm_res32<<<g32, blk, 0, stream>>>(ffb, w2T, b2 + i * D_, h, 1024);
    }

    ln_kernel8<<<gln, blk, 0, stream>>>(h, fng, fnb, tmpb);
    gemm_out32<<<g32, blk, 0, stream>>>(tmpb, woutT, bout, out_main);
}

// Round 15
// 283.666 us; speedup vs baseline: 1.0559x; 1.0015x over previous
//
#include <hip/hip_runtime.h>
#include <hip/hip_bf16.h>
#include <math.h>

#define B_  2
#define L_  2048
#define D_  256
#define H_  8
#define HD_ 32
#define F_  1024
#define LY_ 4
#define M_  (B_*L_)

typedef __attribute__((ext_vector_type(8))) short bf16x8;   // 8 bf16 in 4 VGPRs
typedef __attribute__((ext_vector_type(4))) float f32x4;

static __device__ __forceinline__ short f2bf(float f) {
    return __builtin_bit_cast(short, __float2bfloat16(f));
}

static __device__ __forceinline__ void gload_lds16(const ushort* g, ushort* l) {
    __builtin_amdgcn_global_load_lds(
        (const __attribute__((address_space(1))) void*)g,
        (__attribute__((address_space(3))) void*)l, 16, 0, 0);
}

// ---------------------------------------------------------------------------
// Weight transpose + fp32->bf16:  W[K][N] -> Wt[N][K] bf16  (round-6 verified)
// ---------------------------------------------------------------------------
__global__ __launch_bounds__(256) void transpose_weights(
    const float* __restrict__ Win, const float* __restrict__ Wq,
    const float* __restrict__ Wk,  const float* __restrict__ Wv,
    const float* __restrict__ Wo,  const float* __restrict__ W1,
    const float* __restrict__ W2,  const float* __restrict__ Wout,
    ushort* __restrict__ T)
{
    const int bid = blockIdx.x;
    const float* src; ushort* dst; int K, N, tt;
    if (bid < 64)        { src = Win; dst = T; K = 256; N = 256; tt = bid; }
    else if (bid < 1088) {
        int i = bid - 64; int which = i >> 8; int l = (i >> 6) & 3; tt = i & 63;
        K = 256; N = 256;
        const float* s4[4] = {Wq, Wk, Wv, Wo};
        src = s4[which] + l * 65536;
        dst = T + 65536 * (1 + which * 4 + l);
    } else if (bid < 2112) {
        int i = bid - 1088; int l = i >> 8; tt = i & 255; K = 256; N = 1024;
        src = W1 + l * 262144; dst = T + 65536 * 17 + l * 262144;
    } else if (bid < 3136) {
        int i = bid - 2112; int l = i >> 8; tt = i & 255; K = 1024; N = 256;
        src = W2 + l * 262144; dst = T + 65536 * 17 + 1048576 + l * 262144;
    } else {
        src = Wout; dst = T + 65536 * 17 + 2097152; K = 256; N = 256; tt = bid - 3136;
    }
    const int ntn = N >> 5;
    const int tk = tt / ntn, tn = tt % ntn;
    __shared__ float ld[32][33];
    const int t = threadIdx.x;
    const int r = t >> 3, c4 = (t & 7) * 4;
    float4 v = *reinterpret_cast<const float4*>(&src[(size_t)(tk * 32 + r) * N + tn * 32 + c4]);
    ld[r][c4 + 0] = v.x; ld[r][c4 + 1] = v.y; ld[r][c4 + 2] = v.z; ld[r][c4 + 3] = v.w;
    __syncthreads();
    short4 o;
    o.x = f2bf(ld[c4 + 0][r]);
    o.y = f2bf(ld[c4 + 1][r]);
    o.z = f2bf(ld[c4 + 2][r]);
    o.w = f2bf(ld[c4 + 3][r]);
    *reinterpret_cast<short4*>(&dst[(size_t)(tn * 32 + r) * K + tk * 32 + c4]) = o;
}

// ---------------------------------------------------------------------------
// bf16 MFMA GEMM core v2 (round-6 verified, 64x64 tile).
// ---------------------------------------------------------------------------
__device__ __forceinline__ void gemm_core64(
    const ushort* __restrict__ A, const ushort* __restrict__ Wt, int K,
    int row0, int col0, ushort* sA, ushort* sW, f32x4 acc[2][2])
{
    const int tid  = threadIdx.x;
    const int lane = tid & 63;
    const int wid  = tid >> 6;
    const int wr = wid >> 1, wc = wid & 1;
    const int g = lane >> 4, nn = lane & 15;

    const int r0 = tid >> 3;
    const int sx = ((tid & 7) ^ (r0 & 7)) << 3;

    const ushort* Ap = &A[(size_t)(row0 + r0) * K + sx];
    const ushort* Wp = &Wt[(size_t)(col0 + r0) * K + sx];
    const size_t rstep = (size_t)32 * K;

    ushort* ldsA = sA + wid * 512;
    ushort* ldsW = sW + wid * 512;

    gload_lds16(Ap,         ldsA);
    gload_lds16(Ap + rstep, ldsA + 2048);
    gload_lds16(Wp,         ldsW);
    gload_lds16(Wp + rstep, ldsW + 2048);

    const int ra = (wr * 32 + nn) * 64, rb = ra + 16 * 64;
    const int rc = (wc * 32 + nn) * 64, rd = rc + 16 * 64;
    const int m7 = nn & 7;

    int cur = 0;
    __syncthreads();
    for (int k0 = 0; k0 < K; k0 += 64) {
        if (k0 + 64 < K) {
            ushort* lA = ldsA + (cur ^ 1) * 4096;
            ushort* lW = ldsW + (cur ^ 1) * 4096;
            gload_lds16(Ap + k0 + 64,         lA);
            gload_lds16(Ap + k0 + 64 + rstep, lA + 2048);
            gload_lds16(Wp + k0 + 64,         lW);
            gload_lds16(Wp + k0 + 64 + rstep, lW + 2048);
        }
        const ushort* a = sA + cur * 4096;
        const ushort* w = sW + cur * 4096;
#pragma unroll
        for (int sk = 0; sk < 2; ++sk) {
            const int sw = ((sk * 4 + g) ^ m7) << 3;
            bf16x8 a0 = *reinterpret_cast<const bf16x8*>(&a[ra + sw]);
            bf16x8 a1 = *reinterpret_cast<const bf16x8*>(&a[rb + sw]);
            bf16x8 w0 = *reinterpret_cast<const bf16x8*>(&w[rc + sw]);
            bf16x8 w1 = *reinterpret_cast<const bf16x8*>(&w[rd + sw]);
            acc[0][0] = __builtin_amdgcn_mfma_f32_16x16x32_bf16(a0, w0, acc[0][0], 0, 0, 0);
            acc[0][1] = __builtin_amdgcn_mfma_f32_16x16x32_bf16(a0, w1, acc[0][1], 0, 0, 0);
            acc[1][0] = __builtin_amdgcn_mfma_f32_16x16x32_bf16(a1, w0, acc[1][0], 0, 0, 0);
            acc[1][1] = __builtin_amdgcn_mfma_f32_16x16x32_bf16(a1, w1, acc[1][1], 0, 0, 0);
        }
        __syncthreads();
        cur ^= 1;
    }
}

// ---------------------------------------------------------------------------
// First GEMM: x fp32 -> h fp32 with convert-only A prologue (r14 verified).
// ---------------------------------------------------------------------------
__global__ __launch_bounds__(256) void gemm_first(
    const float* __restrict__ Hin, const ushort* __restrict__ Wt,
    const float* __restrict__ bias, float* __restrict__ Cout)
{
    __shared__ __align__(16) ushort sLN[64 * 264];
    __shared__ __align__(16) ushort sW[2 * 4096];
    const int row0 = blockIdx.y * 64, col0 = blockIdx.x * 64;
    const int tid  = threadIdx.x;
    const int lane = tid & 63;
    const int wid  = tid >> 6;
    const int wr = wid >> 1, wc = wid & 1;
    const int g = lane >> 4, nn = lane & 15;

    const int r0 = tid >> 3;
    const int sx = ((tid & 7) ^ (r0 & 7)) << 3;
    const ushort* Wp = &Wt[(size_t)(col0 + r0) * 256 + sx];
    ushort* ldsW = sW + wid * 512;
    gload_lds16(Wp,            ldsW);
    gload_lds16(Wp + 32 * 256, ldsW + 2048);

    const float4* hp = reinterpret_cast<const float4*>(Hin + (size_t)row0 * D_);
#pragma unroll
    for (int j = 0; j < 16; ++j) {
        const float4 v = hp[j * 256 + tid];
        short4 o = {f2bf(v.x), f2bf(v.y), f2bf(v.z), f2bf(v.w)};
        *reinterpret_cast<short4*>(&sLN[(j * 4 + wid) * 264 + lane * 4]) = o;
    }
    __syncthreads();

    const int ra = (wr * 32 + nn) * 264, rb = ra + 16 * 264;
    const int rc = (wc * 32 + nn) * 64,  rd = rc + 16 * 64;
    const int m7 = nn & 7;
    f32x4 acc[2][2] = {};

    int cur = 0;
#pragma unroll
    for (int k0 = 0; k0 < 256; k0 += 64) {
        if (k0 + 64 < 256) {
            ushort* lW = ldsW + (cur ^ 1) * 4096;
            gload_lds16(Wp + k0 + 64,            lW);
            gload_lds16(Wp + k0 + 64 + 32 * 256, lW + 2048);
        }
        const ushort* w = sW + cur * 4096;
#pragma unroll
        for (int sk = 0; sk < 2; ++sk) {
            const int ac = k0 + sk * 32 + g * 8;
            bf16x8 a0 = *reinterpret_cast<const bf16x8*>(&sLN[ra + ac]);
            bf16x8 a1 = *reinterpret_cast<const bf16x8*>(&sLN[rb + ac]);
            const int sw = ((sk * 4 + g) ^ m7) << 3;
            bf16x8 w0 = *reinterpret_cast<const bf16x8*>(&w[rc + sw]);
            bf16x8 w1 = *reinterpret_cast<const bf16x8*>(&w[rd + sw]);
            acc[0][0] = __builtin_amdgcn_mfma_f32_16x16x32_bf16(a0, w0, acc[0][0], 0, 0, 0);
            acc[0][1] = __builtin_amdgcn_mfma_f32_16x16x32_bf16(a0, w1, acc[0][1], 0, 0, 0);
            acc[1][0] = __builtin_amdgcn_mfma_f32_16x16x32_bf16(a1, w0, acc[1][0], 0, 0, 0);
            acc[1][1] = __builtin_amdgcn_mfma_f32_16x16x32_bf16(a1, w1, acc[1][1], 0, 0, 0);
        }
        __syncthreads();
        cur ^= 1;
    }

#pragma unroll
    for (int mi = 0; mi < 2; ++mi)
#pragma unroll
    for (int ni = 0; ni < 2; ++ni)
#pragma unroll
    for (int r = 0; r < 4; ++r) {
        const int m = row0 + wr * 32 + mi * 16 + g * 4 + r;
        const int c = col0 + wc * 32 + ni * 16 + nn;
        Cout[(size_t)m * D_ + c] = acc[mi][ni][r] + bias[c];
    }
}

// ---------------------------------------------------------------------------
// 32x64-tile core + residual GEMMs (round-13 verified).
// ---------------------------------------------------------------------------
__device__ __forceinline__ void gemm_core32(
    const ushort* __restrict__ A, const ushort* __restrict__ Wt, int K,
    int row0, int col0, ushort* sA, ushort* sW, f32x4 acc[2])
{
    const int tid  = threadIdx.x;
    const int lane = tid & 63;
    const int wid  = tid >> 6;
    const int wr = wid >> 1, wc = wid & 1;
    const int g = lane >> 4, nn = lane & 15;

    const int r0 = tid >> 3;
    const int sx = ((tid & 7) ^ (r0 & 7)) << 3;

    const ushort* Ap = &A[(size_t)(row0 + r0) * K + sx];
    const ushort* Wp = &Wt[(size_t)(col0 + r0) * K + sx];
    const size_t rstep = (size_t)32 * K;

    ushort* ldsA = sA + wid * 512;
    ushort* ldsW = sW + wid * 512;

    gload_lds16(Ap,         ldsA);
    gload_lds16(Wp,         ldsW);
    gload_lds16(Wp + rstep, ldsW + 2048);

    const int ra = (wr * 16 + nn) * 64;
    const int rc = (wc * 32 + nn) * 64, rd = rc + 16 * 64;
    const int m7 = nn & 7;

    int cur = 0;
    __syncthreads();
    for (int k0 = 0; k0 < K; k0 += 64) {
        if (k0 + 64 < K) {
            ushort* lA = ldsA + (cur ^ 1) * 2048;
            ushort* lW = ldsW + (cur ^ 1) * 4096;
            gload_lds16(Ap + k0 + 64,         lA);
            gload_lds16(Wp + k0 + 64,         lW);
            gload_lds16(Wp + k0 + 64 + rstep, lW + 2048);
        }
        const ushort* a = sA + cur * 2048;
        const ushort* w = sW + cur * 4096;
#pragma unroll
        for (int sk = 0; sk < 2; ++sk) {
            const int sw = ((sk * 4 + g) ^ m7) << 3;
            bf16x8 a0 = *reinterpret_cast<const bf16x8*>(&a[ra + sw]);
            bf16x8 w0 = *reinterpret_cast<const bf16x8*>(&w[rc + sw]);
            bf16x8 w1 = *reinterpret_cast<const bf16x8*>(&w[rd + sw]);
            acc[0] = __builtin_amdgcn_mfma_f32_16x16x32_bf16(a0, w0, acc[0], 0, 0, 0);
            acc[1] = __builtin_amdgcn_mfma_f32_16x16x32_bf16(a0, w1, acc[1], 0, 0, 0);
        }
        __syncthreads();
        cur ^= 1;
    }
}

__global__ __launch_bounds__(256) void gemm_res32(
    const ushort* __restrict__ A, const ushort* __restrict__ Wt,
    const float* __restrict__ bias, float* __restrict__ C, int K)
{
    __shared__ __align__(16) ushort sA[2 * 2048];
    __shared__ __align__(16) ushort sW[2 * 4096];
    const int row0 = blockIdx.y * 32, col0 = blockIdx.x * 64;
    f32x4 acc[2] = {};
    gemm_core32(A, Wt, K, row0, col0, sA, sW, acc);

    const int lane = threadIdx.x & 63;
    const int wid  = threadIdx.x >> 6;
    const int wr = wid >> 1, wc = wid & 1;
    const int g = lane >> 4, nn = lane & 15;
#pragma unroll
    for (int ni = 0; ni < 2; ++ni)
#pragma unroll
    for (int r = 0; r < 4; ++r) {
        const int m = row0 + wr * 16 + g * 4 + r;
        const int c = col0 + wc * 32 + ni * 16 + nn;
        C[(size_t)m * D_ + c] += acc[ni][r] + bias[c];
    }
}

__global__ __launch_bounds__(256) void gemm_out32(
    const ushort* __restrict__ A, const ushort* __restrict__ Wt,
    const float* __restrict__ bias, float* __restrict__ Cout)
{
    __shared__ __align__(16) ushort sA[2 * 2048];
    __shared__ __align__(16) ushort sW[2 * 4096];
    const int row0 = blockIdx.y * 32, col0 = blockIdx.x * 64;
    f32x4 acc[2] = {};
    gemm_core32(A, Wt, 256, row0, col0, sA, sW, acc);

    const int lane = threadIdx.x & 63;
    const int wid  = threadIdx.x >> 6;
    const int wr = wid >> 1, wc = wid & 1;
    const int g = lane >> 4, nn = lane & 15;
#pragma unroll
    for (int ni = 0; ni < 2; ++ni)
#pragma unroll
    for (int r = 0; r < 4; ++r) {
        const int m = row0 + wr * 16 + g * 4 + r;
        const int c = col0 + wc * 32 + ni * 16 + nn;
        Cout[(size_t)m * D_ + c] = acc[ni][r] + bias[c];
    }
}

// ---------------------------------------------------------------------------
// Generic 64-tile GEMM + epilogue (FF1 GELU path).
// ---------------------------------------------------------------------------
template<int EPI, int OUTBF>
__global__ __launch_bounds__(256) void gemm_bf16(
    const ushort* __restrict__ A, const ushort* __restrict__ Wt,
    const float* __restrict__ bias, const float* __restrict__ res,
    void* __restrict__ Cout, int M, int N, int K)
{
    __shared__ __align__(16) ushort sA[2 * 4096];
    __shared__ __align__(16) ushort sW[2 * 4096];
    const int row0 = blockIdx.y * 64, col0 = blockIdx.x * 64;
    f32x4 acc[2][2] = {};
    gemm_core64(A, Wt, K, row0, col0, sA, sW, acc);

    const int lane = threadIdx.x & 63;
    const int wid  = threadIdx.x >> 6;
    const int wr = wid >> 1, wc = wid & 1;
    const int g = lane >> 4, nn = lane & 15;
#pragma unroll
    for (int mi = 0; mi < 2; ++mi)
#pragma unroll
    for (int ni = 0; ni < 2; ++ni)
#pragma unroll
    for (int r = 0; r < 4; ++r) {
        const int m = row0 + wr * 32 + mi * 16 + g * 4 + r;
        const int c = col0 + wc * 32 + ni * 16 + nn;
        float v = acc[mi][ni][r] + bias[c];
        if (EPI == 1) v = 0.5f * v * (1.0f + erff(v * 0.70710678118654752f));
        if (EPI == 2) v += res[(size_t)m * N + c];
        if (OUTBF) ((ushort*)Cout)[(size_t)m * N + c] = (ushort)f2bf(v);
        else       ((float*)Cout)[(size_t)m * N + c] = v;
    }
}

// ---------------------------------------------------------------------------
// Fused QKV GEMM (round-6 verified).
// ---------------------------------------------------------------------------
__global__ __launch_bounds__(256) void gemm_qkv(
    const ushort* __restrict__ A,
    const ushort* __restrict__ WqT, const ushort* __restrict__ WkT,
    const ushort* __restrict__ WvT,
    const float* __restrict__ bq, const float* __restrict__ bk,
    const float* __restrict__ bv,
    ushort* __restrict__ Qb, ushort* __restrict__ Kb, ushort* __restrict__ Vt)
{
    __shared__ __align__(16) ushort sA[2 * 4096];
    __shared__ __align__(16) ushort sW[2 * 4096];
    const int nb = blockIdx.x;
    const int wsel = nb >> 2;
    const int col0 = (nb & 3) * 64;
    const int row0 = blockIdx.y * 64;
    const ushort* Wt = (wsel == 0) ? WqT : (wsel == 1) ? WkT : WvT;
    const float* bias = (wsel == 0) ? bq : (wsel == 1) ? bk : bv;

    f32x4 acc[2][2] = {};
    gemm_core64(A, Wt, 256, row0, col0, sA, sW, acc);

    const int lane = threadIdx.x & 63;
    const int wid  = threadIdx.x >> 6;
    const int wr = wid >> 1, wc = wid & 1;
    const int g = lane >> 4, nn = lane & 15;
    ushort* QK = (wsel == 0) ? Qb : Kb;
#pragma unroll
    for (int mi = 0; mi < 2; ++mi)
#pragma unroll
    for (int ni = 0; ni < 2; ++ni)
#pragma unroll
    for (int r = 0; r < 4; ++r) {
        const int m = row0 + wr * 32 + mi * 16 + g * 4 + r;
        const int c = col0 + wc * 32 + ni * 16 + nn;
        const float v = acc[mi][ni][r] + bias[c];
        if (wsel < 2) {
            QK[(size_t)m * D_ + c] = (ushort)f2bf(v);
        } else {
            const int b = m >> 11, l = m & 2047;
            const int h = c >> 5,  d = c & 31;
            Vt[(size_t)((b * 8 + h) * 32 + d) * L_ + l] = (ushort)f2bf(v);
        }
    }
}

// ---------------------------------------------------------------------------
// LayerNorm v2 (round-14 verified): 8 rows/block, float4 loads, butterfly.
// ---------------------------------------------------------------------------
__global__ __launch_bounds__(256) void ln_kernel8(
    const float* __restrict__ x, const float* __restrict__ g,
    const float* __restrict__ b, ushort* __restrict__ y)
{
    const int tid  = threadIdx.x;
    const int row  = blockIdx.x * 8 + (tid >> 5);
    const int l    = tid & 31;
    const float* xp = x + (size_t)row * D_ + l * 8;

    float4 v0 = *reinterpret_cast<const float4*>(xp);
    float4 v1 = *reinterpret_cast<const float4*>(xp + 4);

    float s  = v0.x + v0.y + v0.z + v0.w + v1.x + v1.y + v1.z + v1.w;
    float s2 = v0.x*v0.x + v0.y*v0.y + v0.z*v0.z + v0.w*v0.w
             + v1.x*v1.x + v1.y*v1.y + v1.z*v1.z + v1.w*v1.w;
    s  += __shfl_xor(s, 1);  s  += __shfl_xor(s, 2);  s  += __shfl_xor(s, 4);
    s  += __shfl_xor(s, 8);  s  += __shfl_xor(s, 16);
    s2 += __shfl_xor(s2, 1); s2 += __shfl_xor(s2, 2); s2 += __shfl_xor(s2, 4);
    s2 += __shfl_xor(s2, 8); s2 += __shfl_xor(s2, 16);

    const float m   = s * (1.0f / D_);
    const float var = s2 * (1.0f / D_) - m * m;
    const float r   = rsqrtf(var + 1e-5f);

    const float4 g0 = reinterpret_cast<const float4*>(g)[l * 2];
    const float4 g1 = reinterpret_cast<const float4*>(g)[l * 2 + 1];
    const float4 b0 = reinterpret_cast<const float4*>(b)[l * 2];
    const float4 b1 = reinterpret_cast<const float4*>(b)[l * 2 + 1];

    short4 o0, o1;
    o0.x = f2bf((v0.x - m) * r * g0.x + b0.x);
    o0.y = f2bf((v0.y - m) * r * g0.y + b0.y);
    o0.z = f2bf((v0.z - m) * r * g0.z + b0.z);
    o0.w = f2bf((v0.w - m) * r * g0.w + b0.w);
    o1.x = f2bf((v1.x - m) * r * g1.x + b1.x);
    o1.y = f2bf((v1.y - m) * r * g1.y + b1.y);
    o1.z = f2bf((v1.z - m) * r * g1.z + b1.z);
    o1.w = f2bf((v1.w - m) * r * g1.w + b1.w);
    ushort* yp = y + (size_t)row * D_ + l * 8;
    *reinterpret_cast<short4*>(yp)     = o0;
    *reinterpret_cast<short4*>(yp + 4) = o1;
}

// ---------------------------------------------------------------------------
// MFMA evidence attention v8: depth-2 K/V prefetch + RAW BARRIER sync.
// __syncthreads' vmcnt(0) drain defeated the depth-2 pipeline (r12 lesson);
// replaced with: lgkmcnt(0) (ds_writes visible) + s_barrier + IR fence.
// In-flight K/V global loads now SPAN barriers; the compiler's counted
// vmcnt wait at the ds_write (reg dep, issued 2 tile-computes earlier) is
// the only wait. Buffer reuse safe: write(buf) at iter i vs reads(buf) at
// iter i-2 are separated by the intervening barrier (reads' lgkm waits
// complete before that barrier). Math bit-identical to r12/r14.
// ---------------------------------------------------------------------------
__global__ __launch_bounds__(256) void attn_mfma(
    const ushort* __restrict__ Qb, const ushort* __restrict__ Kb,
    const ushort* __restrict__ Vt, ushort* __restrict__ O,
    float* __restrict__ unc, const float* __restrict__ ev_scale,
    const float* __restrict__ ev_bias, int layer,
    float* __restrict__ out_unc, float* __restrict__ out_abst)
{
    const int bh = blockIdx.y;
    const int b  = bh >> 3;
    const int h  = bh & 7;
    const int tid  = threadIdx.x;
    const int wv   = tid >> 6;
    const int lane = tid & 63;
    const int g = lane >> 4;
    const int n = lane & 15;
    const int q  = blockIdx.x * 64 + wv * 16 + n;
    const float scale = ev_scale[layer];
    const float cb    = 1.0f + ev_bias[layer];
    const float isq   = 0.17677669529663687f;   // 1/sqrt(32)

    __shared__ __align__(16) ushort sK[2][64][40];
    __shared__ __align__(16) ushort sV[2][32][72];

    const size_t qk0 = (size_t)b * L_ * D_ + h * HD_;

    bf16x8 qf;
    {
        const bf16x8 qr = *reinterpret_cast<const bf16x8*>(&Qb[qk0 + (size_t)q * D_ + g * 8]);
#pragma unroll
        for (int j = 0; j < 8; ++j) {
            const float qv = __builtin_bit_cast(float, ((unsigned)(unsigned short)qr[j]) << 16);
            qf[j] = f2bf(qv * isq);
        }
    }
    bf16x8 ones;
#pragma unroll
    for (int j = 0; j < 8; ++j) ones[j] = (short)0x3F80;

    const int krow = tid >> 2, kch = (tid & 3) * 8;
    const int vrow = tid >> 3, vch = (tid & 7) * 8;
    const ushort* ksrc = Kb + qk0 + (size_t)krow * D_ + kch;
    const ushort* vsrc = Vt + (size_t)((b * 8 + h) * 32 + vrow) * L_ + vch;

    f32x4 acc0 = {0.f, 0.f, 0.f, 0.f};
    f32x4 acc1 = {0.f, 0.f, 0.f, 0.f};
    f32x4 accS = {0.f, 0.f, 0.f, 0.f};
    const f32x4 zero = {0.f, 0.f, 0.f, 0.f};

    bf16x8 kA = *reinterpret_cast<const bf16x8*>(ksrc);
    bf16x8 vA = *reinterpret_cast<const bf16x8*>(vsrc);
    bf16x8 kB = *reinterpret_cast<const bf16x8*>(ksrc + (size_t)64 * D_);
    bf16x8 vB = *reinterpret_cast<const bf16x8*>(vsrc + 64);

    // ds_writes drained (cross-wave visible) -> barrier -> fence pins reads
    // after it. Global loads remain in flight across the barrier.
#define SYNC_BAR()                                                    \
    do {                                                              \
        asm volatile("s_waitcnt lgkmcnt(0)" ::: "memory");            \
        __builtin_amdgcn_s_barrier();                                 \
        asm volatile("" ::: "memory");                                \
    } while (0)

#define ATTN_TILE(BUF)                                                          \
    do {                                                                        \
        _Pragma("unroll")                                                       \
        for (int tt = 0; tt < 64; tt += 32) {                                   \
            bf16x8 kf0 = *reinterpret_cast<const bf16x8*>(&sK[BUF][tt + n][g * 8]);      \
            bf16x8 kf1 = *reinterpret_cast<const bf16x8*>(&sK[BUF][tt + 16 + n][g * 8]); \
            f32x4 s0 = __builtin_amdgcn_mfma_f32_16x16x32_bf16(kf0, qf, zero, 0, 0, 0);  \
            f32x4 s1 = __builtin_amdgcn_mfma_f32_16x16x32_bf16(kf1, qf, zero, 0, 0, 0);  \
            short4 va = *reinterpret_cast<const short4*>(&sV[BUF][n][tt + g * 4]);       \
            short4 vb = *reinterpret_cast<const short4*>(&sV[BUF][n][tt + 16 + g * 4]);  \
            short4 vc = *reinterpret_cast<const short4*>(&sV[BUF][n + 16][tt + g * 4]);  \
            short4 vd = *reinterpret_cast<const short4*>(&sV[BUF][n + 16][tt + 16 + g * 4]); \
            bf16x8 vf0 = {va.x, va.y, va.z, va.w, vb.x, vb.y, vb.z, vb.w};      \
            bf16x8 vf1 = {vc.x, vc.y, vc.z, vc.w, vd.x, vd.y, vd.z, vd.w};      \
            bf16x8 pa;                                                          \
            _Pragma("unroll")                                                   \
            for (int r = 0; r < 4; ++r) pa[r]     = f2bf(fmaf(__expf(s0[r]), scale, cb)); \
            _Pragma("unroll")                                                   \
            for (int r = 0; r < 4; ++r) pa[r + 4] = f2bf(fmaf(__expf(s1[r]), scale, cb)); \
            acc0 = __builtin_amdgcn_mfma_f32_16x16x32_bf16(vf0, pa, acc0, 0, 0, 0); \
            acc1 = __builtin_amdgcn_mfma_f32_16x16x32_bf16(vf1, pa, acc1, 0, 0, 0); \
            accS = __builtin_amdgcn_mfma_f32_16x16x32_bf16(ones, pa, accS, 0, 0, 0); \
        }                                                                       \
    } while (0)

    for (int t = 0; t < L_; t += 128) {
        *reinterpret_cast<bf16x8*>(&sK[0][krow][kch]) = kA;
        *reinterpret_cast<bf16x8*>(&sV[0][vrow][vch]) = vA;
        if (t + 128 < L_) {
            kA = *reinterpret_cast<const bf16x8*>(ksrc + (size_t)(t + 128) * D_);
            vA = *reinterpret_cast<const bf16x8*>(vsrc + (t + 128));
        }
        SYNC_BAR();
        ATTN_TILE(0);

        *reinterpret_cast<bf16x8*>(&sK[1][krow][kch]) = kB;
        *reinterpret_cast<bf16x8*>(&sV[1][vrow][vch]) = vB;
        if (t + 192 < L_) {
            kB = *reinterpret_cast<const bf16x8*>(ksrc + (size_t)(t + 192) * D_);
            vB = *reinterpret_cast<const bf16x8*>(vsrc + (t + 192));
        }
        SYNC_BAR();
        ATTN_TILE(1);
    }
#undef ATTN_TILE
#undef SYNC_BAR

    const float inv = 1.0f / accS[0];

    ushort* op = &O[qk0 + (size_t)q * D_ + g * 4];
    short4 o0 = {f2bf(acc0[0] * inv), f2bf(acc0[1] * inv), f2bf(acc0[2] * inv), f2bf(acc0[3] * inv)};
    short4 o1 = {f2bf(acc1[0] * inv), f2bf(acc1[1] * inv), f2bf(acc1[2] * inv), f2bf(acc1[3] * inv)};
    *reinterpret_cast<short4*>(op)      = o0;
    *reinterpret_cast<short4*>(op + 16) = o1;

    if (g == 0) {
        const float u = (float)L_ * inv;
        const int uidx = bh * L_ + q;
        if (layer == 0) {
            unc[uidx] = u;                      // '=' : deterministic across replays
        } else if (layer < LY_ - 1) {
            unc[uidx] += u;
        } else {
            const float avg = (unc[uidx] + u) * 0.25f;
            out_unc[uidx]  = avg;
            out_abst[uidx] = (avg > 0.3f) ? 1.0f : 0.0f;
        }
    }
}

// ---------------------------------------------------------------------------
extern "C" void kernel_launch(void* const* d_in, const int* in_sizes, int n_in,
                              void* d_out, int out_size, void* d_ws, size_t ws_size,
                              hipStream_t stream)
{
    const float* x    = (const float*)d_in[0];
    const float* Win  = (const float*)d_in[1];
    const float* bin_ = (const float*)d_in[2];
    const float* Wq   = (const float*)d_in[3];
    const float* bq   = (const float*)d_in[4];
    const float* Wk   = (const float*)d_in[5];
    const float* bk   = (const float*)d_in[6];
    const float* Wv   = (const float*)d_in[7];
    const float* bv   = (const float*)d_in[8];
    const float* Wo   = (const float*)d_in[9];
    const float* bo   = (const float*)d_in[10];
    const float* evs  = (const float*)d_in[11];
    const float* evb  = (const float*)d_in[12];
    const float* W1   = (const float*)d_in[13];
    const float* b1   = (const float*)d_in[14];
    const float* W2   = (const float*)d_in[15];
    const float* b2   = (const float*)d_in[16];
    const float* n1g  = (const float*)d_in[17];
    const float* n1b  = (const float*)d_in[18];
    const float* n2g  = (const float*)d_in[19];
    const float* n2b  = (const float*)d_in[20];
    const float* fng  = (const float*)d_in[21];
    const float* fnb  = (const float*)d_in[22];
    const float* Wout = (const float*)d_in[23];
    const float* bout = (const float*)d_in[24];

    char* ws = (char*)d_ws;
    float*  h    = (float*) (ws);                  // 4 MB fp32 residual stream
    ushort* tmpb = (ushort*)(ws + (4  << 20));     // 2 MB bf16 (LN out)
    ushort* Qb   = (ushort*)(ws + (6  << 20));     // 2 MB
    ushort* Kb   = (ushort*)(ws + (8  << 20));     // 2 MB
    ushort* Vt   = (ushort*)(ws + (10 << 20));     // 2 MB (transposed V)
    ushort* Ob   = (ushort*)(ws + (12 << 20));     // 2 MB (attn out)
    ushort* ffb  = (ushort*)(ws + (6  << 20));     // 8 MB, overlays Qb..Ob (dead by FF1)
    float*  unc  = (float*) (ws + (14 << 20));     // 128 KB
    ushort* T    = (ushort*)(ws + (15 << 20));     // 6.55 MB transposed bf16 weights

    ushort* winT  = T;
    ushort* woutT = T + 65536 * 17 + 2097152;

    float* out_main = (float*)d_out;
    float* out_unc  = out_main + M_ * D_;
    float* out_abst = out_unc + B_ * H_ * L_;

    const dim3 blk(256);
    const dim3 g64(4, 64);      // 64-tile GEMMs
    const dim3 g32(4, 128);     // 32x64-tile GEMMs (2 blocks/CU)
    const dim3 g1024(16, 64);   // N=1024 GEMM
    const dim3 gqkv(12, 64);
    const dim3 gattn(L_ / 64, B_ * H_);
    const dim3 gln(M_ / 8);

    transpose_weights<<<3200, blk, 0, stream>>>(Win, Wq, Wk, Wv, Wo, W1, W2, Wout, T);
    gemm_first<<<g64, blk, 0, stream>>>(x, winT, bin_, h);

    for (int i = 0; i < LY_; ++i) {
        ushort* wqT = T + 65536 * (1 + i);
        ushort* wkT = T + 65536 * (5 + i);
        ushort* wvT = T + 65536 * (9 + i);
        ushort* woT = T + 65536 * (13 + i);
        ushort* w1T = T + 65536 * 17 + i * 262144;
        ushort* w2T = T + 65536 * 17 + 1048576 + i * 262144;

        ln_kernel8<<<gln, blk, 0, stream>>>(h, n1g + i * D_, n1b + i * D_, tmpb);
        gemm_qkv<<<gqkv, blk, 0, stream>>>(tmpb, wqT, wkT, wvT,
                                           bq + i * D_, bk + i * D_, bv + i * D_,
                                           Qb, Kb, Vt);
        attn_mfma<<<gattn, blk, 0, stream>>>(Qb, Kb, Vt, Ob, unc, evs, evb, i,
                                             out_unc, out_abst);
        gemm_res32<<<g32, blk, 0, stream>>>(Ob, woT, bo + i * D_, h, 256);
        ln_kernel8<<<gln, blk, 0, stream>>>(h, n2g + i * D_, n2b + i * D_, tmpb);
        gemm_bf16<1, 1><<<g1024, blk, 0, stream>>>(tmpb, w1T, b1 + i * F_, nullptr, ffb, M_, F_, D_);
        gemm_res32<<<g32, blk, 0, stream>>>(ffb, w2T, b2 + i * D_, h, 1024);
    }

    ln_kernel8<<<gln, blk, 0, stream>>>(h, fng, fnb, tmpb);
    gemm_out32<<<g32, blk, 0, stream>>>(tmpb, woutT, bout, out_main);
}